// Round 1
// baseline (990.117 us; speedup 1.0000x reference)
//
#include <hip/hip_runtime.h>

// GAT (3-layer) on MI355X.
// Strategy: build CSR by dst once per launch (graph identical across layers),
// then per layer: GEMM (h = X@W) -> per-node logit parts -> per-dst-node
// softmax-weighted aggregation (one wave per node, no float atomics).
// Softmax max-subtraction is skipped (shift-invariant; logits are O(8)).

constexpr int N_NODES = 100000;
constexpr int E_IN    = 1600000;
constexpr int E_TOT   = E_IN + N_NODES;   // + self loops
constexpr float NEG   = 0.2f;

// ---------------- CSR build ----------------

__global__ void count_deg(const int* __restrict__ ei, int* __restrict__ deg) {
    int e = blockIdx.x * 256 + threadIdx.x;
    if (e >= E_TOT) return;
    int d = (e < E_IN) ? ei[E_IN + e] : (e - E_IN);
    atomicAdd(&deg[d], 1);
}

__global__ void scan_partial(const int* __restrict__ deg, int* __restrict__ bsum) {
    __shared__ int lds[256];
    int i = blockIdx.x * 256 + threadIdx.x;
    int v = (i < N_NODES) ? deg[i] : 0;
    lds[threadIdx.x] = v;
    __syncthreads();
    for (int s = 128; s > 0; s >>= 1) {
        if (threadIdx.x < s) lds[threadIdx.x] += lds[threadIdx.x + s];
        __syncthreads();
    }
    if (threadIdx.x == 0) bsum[blockIdx.x] = lds[0];
}

// single wave scans the per-block sums
__global__ void scan_bsums(const int* __restrict__ bsum, int* __restrict__ bofs,
                           int* __restrict__ rowptr, int nb) {
    int lane = threadIdx.x;  // 64 threads
    int carry = 0;
    for (int base = 0; base < nb; base += 64) {
        int i = base + lane;
        int v = (i < nb) ? bsum[i] : 0;
        int x = v;
        #pragma unroll
        for (int d = 1; d < 64; d <<= 1) {
            int y = __shfl_up(x, d);
            if (lane >= d) x += y;
        }
        int excl = x - v + carry;
        if (i < nb) bofs[i] = excl;
        carry += __shfl(x, 63);
    }
    if (lane == 0) rowptr[N_NODES] = carry;  // == E_TOT
}

__global__ void scan_write(const int* __restrict__ deg, const int* __restrict__ bofs,
                           int* __restrict__ rowptr, int* __restrict__ cursor) {
    __shared__ int a[256], b[256];
    int t = threadIdx.x;
    int i = blockIdx.x * 256 + t;
    int v = (i < N_NODES) ? deg[i] : 0;
    a[t] = v;
    __syncthreads();
    int* src = a; int* dst = b;
    for (int d = 1; d < 256; d <<= 1) {
        dst[t] = src[t] + ((t >= d) ? src[t - d] : 0);
        __syncthreads();
        int* tmp = src; src = dst; dst = tmp;
    }
    int excl = src[t] - v + bofs[blockIdx.x];
    if (i < N_NODES) { rowptr[i] = excl; cursor[i] = excl; }
}

__global__ void fill_csr(const int* __restrict__ ei, int* __restrict__ cursor,
                         int* __restrict__ srclist) {
    int e = blockIdx.x * 256 + threadIdx.x;
    if (e >= E_TOT) return;
    int s, d;
    if (e < E_IN) { s = ei[e]; d = ei[E_IN + e]; }
    else          { s = e - E_IN; d = s; }
    int pos = atomicAdd(&cursor[d], 1);
    srclist[pos] = s;
}

// ---------------- GEMM: Y[N,COUT] = X[N,128] @ W[128,COUT] ----------------
// COUT=128: 32 rows/block, 4 rows x 4 cols per thread, W staged in 2x 32KB halves.
// COUT=32 : 64 rows/block, 2 rows x 4 cols per thread, W staged whole (16KB).

template<int COUT>
__global__ __launch_bounds__(256) void gemm_k(const float* __restrict__ X,
                                              const float* __restrict__ Wg,
                                              float* __restrict__ Y) {
    constexpr int CG  = COUT / 4;               // col groups of 4
    constexpr int RG  = 256 / CG;               // row groups
    constexpr int RPT = (COUT == 128) ? 4 : 2;  // rows per thread
    constexpr int RB  = RG * RPT;               // rows per block
    constexpr int KCH = (COUT == 128) ? 64 : 128;  // k-rows per W stage
    constexpr int XSTR = 132;                   // padded X row stride (bank-conflict)

    __shared__ float Wl[KCH * COUT];
    __shared__ float Xl[RB * XSTR];

    int t = threadIdx.x;
    int rbase = blockIdx.x * RB;

    // stage X tile (row-clamped for the tail block)
    for (int i = t; i < RB * 32; i += 256) {
        int r = i >> 5, c4 = i & 31;
        int gr = rbase + r; if (gr >= N_NODES) gr = N_NODES - 1;
        *(float4*)&Xl[r * XSTR + c4 * 4] = *(const float4*)&X[gr * 128 + c4 * 4];
    }

    int cg = t % CG, rg = t / CG;
    int c0 = cg * 4, r0 = rg * RPT;
    float4 acc[RPT];
    #pragma unroll
    for (int i = 0; i < RPT; i++) acc[i] = make_float4(0.f, 0.f, 0.f, 0.f);

    for (int ph = 0; ph < 128 / KCH; ++ph) {
        __syncthreads();
        for (int i = t * 4; i < KCH * COUT; i += 1024)
            *(float4*)&Wl[i] = *(const float4*)&Wg[ph * KCH * COUT + i];
        __syncthreads();
        for (int k4 = 0; k4 < KCH / 4; ++k4) {
            int kb = ph * KCH + k4 * 4;
            float4 wv[4], xv[RPT];
            #pragma unroll
            for (int kk = 0; kk < 4; kk++) wv[kk] = *(float4*)&Wl[(k4 * 4 + kk) * COUT + c0];
            #pragma unroll
            for (int i = 0; i < RPT; i++) xv[i] = *(float4*)&Xl[(r0 + i) * XSTR + kb];
            #pragma unroll
            for (int i = 0; i < RPT; i++) {
                const float* xs = (const float*)&xv[i];
                #pragma unroll
                for (int kk = 0; kk < 4; kk++) {
                    acc[i].x += xs[kk] * wv[kk].x;
                    acc[i].y += xs[kk] * wv[kk].y;
                    acc[i].z += xs[kk] * wv[kk].z;
                    acc[i].w += xs[kk] * wv[kk].w;
                }
            }
        }
    }
    #pragma unroll
    for (int i = 0; i < RPT; i++) {
        int gr = rbase + r0 + i;
        if (gr < N_NODES) *(float4*)&Y[gr * COUT + c0] = acc[i];
    }
}

// ---------------- per-node logit parts ----------------
// al_s[n,h] = sum_c h[n,h,c]*a_src[h,c] ; al_d likewise.

template<int H, int HID>
__global__ void logits_k(const float* __restrict__ Hb, const float* __restrict__ a_src,
                         const float* __restrict__ a_dst,
                         float* __restrict__ als, float* __restrict__ ald) {
    int id = blockIdx.x * 256 + threadIdx.x;
    if (id >= N_NODES * H) return;
    int n = id / H, h = id % H;
    const float* row = &Hb[(n * H + h) * HID];
    float s = 0.f, dd = 0.f;
    #pragma unroll
    for (int j = 0; j < HID; j += 4) {
        float4 hv = *(const float4*)&row[j];
        float4 as = *(const float4*)&a_src[h * HID + j];
        float4 av = *(const float4*)&a_dst[h * HID + j];
        s  += hv.x * as.x + hv.y * as.y + hv.z * as.z + hv.w * as.w;
        dd += hv.x * av.x + hv.y * av.y + hv.z * av.z + hv.w * av.w;
    }
    als[id] = s; ald[id] = dd;
}

// ---------------- aggregation (softmax + weighted sum), one wave per node ----
// Layers 1&2: Ctot=128, H=8, HID=16; lane owns channels {lane, lane+64};
// heads lane>>4 and lane>>4 + 4. Bias + ReLU fused.

__global__ __launch_bounds__(256) void agg128(const float* __restrict__ Hb,
        const float* __restrict__ als, const float* __restrict__ ald,
        const int* __restrict__ rowptr, const int* __restrict__ srclist,
        const float* __restrict__ bias, float* __restrict__ out) {
    int wave = (blockIdx.x * 256 + threadIdx.x) >> 6;
    int lane = threadIdx.x & 63;
    if (wave >= N_NODES) return;
    int d = wave;
    int c1 = lane, c2 = lane + 64;
    int h1 = lane >> 4, h2 = h1 + 4;
    float ad1 = ald[d * 8 + h1], ad2 = ald[d * 8 + h2];
    float acc1 = 0.f, acc2 = 0.f, den1 = 0.f, den2 = 0.f;
    int beg = rowptr[d], end = rowptr[d + 1];
    for (int j = beg; j < end; ++j) {
        int s = srclist[j];
        float l1 = als[s * 8 + h1] + ad1;
        float l2 = als[s * 8 + h2] + ad2;
        l1 = l1 > 0.f ? l1 : NEG * l1;
        l2 = l2 > 0.f ? l2 : NEG * l2;
        float w1 = __expf(l1), w2 = __expf(l2);
        den1 += w1; den2 += w2;
        acc1 += w1 * Hb[s * 128 + c1];
        acc2 += w2 * Hb[s * 128 + c2];
    }
    float o1 = acc1 / den1 + bias[c1]; o1 = o1 > 0.f ? o1 : 0.f;
    float o2 = acc2 / den2 + bias[c2]; o2 = o2 > 0.f ? o2 : 0.f;
    out[d * 128 + c1] = o1;
    out[d * 128 + c2] = o2;
}

// Layer 3: Ctot=32, H=1, no relu; two nodes per wave (half-wave each).
__global__ __launch_bounds__(256) void agg32(const float* __restrict__ Hb,
        const float* __restrict__ als, const float* __restrict__ ald,
        const int* __restrict__ rowptr, const int* __restrict__ srclist,
        const float* __restrict__ bias, float* __restrict__ out) {
    int wave = (blockIdx.x * 256 + threadIdx.x) >> 6;
    int lane = threadIdx.x & 63;
    int d = wave * 2 + (lane >> 5);
    int c = lane & 31;
    if (d >= N_NODES) return;
    float adv = ald[d];
    float acc = 0.f, den = 0.f;
    int beg = rowptr[d], end = rowptr[d + 1];
    for (int j = beg; j < end; ++j) {
        int s = srclist[j];
        float l = als[s] + adv;
        l = l > 0.f ? l : NEG * l;
        float w = __expf(l);
        den += w;
        acc += w * Hb[s * 32 + c];
    }
    out[d * 32 + c] = acc / den + bias[c];
}

// ---------------- global mean pool ----------------
__global__ void pool32(const float* __restrict__ h3, float* __restrict__ outp) {
    __shared__ float lds[256];
    int t = threadIdx.x;
    int c = t & 31, g = t >> 5;  // 8 node-groups x 32 channels
    float acc = 0.f;
    for (int n = blockIdx.x * 8 + g; n < N_NODES; n += gridDim.x * 8)
        acc += h3[n * 32 + c];
    lds[t] = acc;
    __syncthreads();
    if (g == 0) {
        float s = 0.f;
        for (int gg = 0; gg < 8; ++gg) s += lds[gg * 32 + c];
        atomicAdd(&outp[c], s * (1.0f / N_NODES));
    }
}

// ---------------- launch ----------------

extern "C" void kernel_launch(void* const* d_in, const int* in_sizes, int n_in,
                              void* d_out, int out_size, void* d_ws, size_t ws_size,
                              hipStream_t stream) {
    (void)in_sizes; (void)n_in; (void)out_size; (void)ws_size;
    const float* x   = (const float*)d_in[0];
    const int*   ei  = (const int*)d_in[1];
    const float* W1  = (const float*)d_in[2];
    const float* as1 = (const float*)d_in[3];
    const float* ad1 = (const float*)d_in[4];
    const float* b1  = (const float*)d_in[5];
    const float* W2  = (const float*)d_in[6];
    const float* as2 = (const float*)d_in[7];
    const float* ad2 = (const float*)d_in[8];
    const float* b2  = (const float*)d_in[9];
    const float* W3  = (const float*)d_in[10];
    const float* as3 = (const float*)d_in[11];
    const float* ad3 = (const float*)d_in[12];
    const float* b3  = (const float*)d_in[13];

    char* ws = (char*)d_ws;
    size_t off = 0;
    auto carve = [&](size_t bytes) { void* p = ws + off; off += (bytes + 255) & ~size_t(255); return p; };
    float* bufH    = (float*)carve(size_t(N_NODES) * 128 * 4);  // h = X@W
    float* bufF    = (float*)carve(size_t(N_NODES) * 128 * 4);  // aggregated features
    float* als     = (float*)carve(size_t(N_NODES) * 8 * 4);
    float* ald     = (float*)carve(size_t(N_NODES) * 8 * 4);
    int*   deg     = (int*)carve(size_t(N_NODES) * 4);
    int*   rowptr  = (int*)carve(size_t(N_NODES + 1) * 4);
    int*   cursor  = (int*)carve(size_t(N_NODES) * 4);
    int*   bsum    = (int*)carve(512 * 4);
    int*   bofs    = (int*)carve(512 * 4);
    int*   srclist = (int*)carve(size_t(E_TOT) * 4);

    const int SCAN_B = (N_NODES + 255) / 256;          // 391
    const int EDGE_B = (E_TOT + 255) / 256;            // 6641

    hipMemsetAsync(deg, 0, size_t(N_NODES) * 4, stream);
    hipMemsetAsync(d_out, 0, 32 * 4, stream);

    // CSR build (graph shared by all 3 layers)
    count_deg  <<<EDGE_B, 256, 0, stream>>>(ei, deg);
    scan_partial<<<SCAN_B, 256, 0, stream>>>(deg, bsum);
    scan_bsums <<<1, 64, 0, stream>>>(bsum, bofs, rowptr, SCAN_B);
    scan_write <<<SCAN_B, 256, 0, stream>>>(deg, bofs, rowptr, cursor);
    fill_csr   <<<EDGE_B, 256, 0, stream>>>(ei, cursor, srclist);

    // layer 1: x[N,128] -> bufF[N,128]
    gemm_k<128><<<N_NODES / 32, 256, 0, stream>>>(x, W1, bufH);
    logits_k<8, 16><<<(N_NODES * 8 + 255) / 256, 256, 0, stream>>>(bufH, as1, ad1, als, ald);
    agg128<<<(N_NODES * 64) / 256, 256, 0, stream>>>(bufH, als, ald, rowptr, srclist, b1, bufF);

    // layer 2: bufF -> bufF
    gemm_k<128><<<N_NODES / 32, 256, 0, stream>>>(bufF, W2, bufH);
    logits_k<8, 16><<<(N_NODES * 8 + 255) / 256, 256, 0, stream>>>(bufH, as2, ad2, als, ald);
    agg128<<<(N_NODES * 64) / 256, 256, 0, stream>>>(bufH, als, ald, rowptr, srclist, b2, bufF);

    // layer 3: bufF[N,128] -> bufH[N,32] -> bufF[N,32] -> pool
    gemm_k<32><<<(N_NODES + 63) / 64, 256, 0, stream>>>(bufF, W3, bufH);
    logits_k<1, 32><<<(N_NODES + 255) / 256, 256, 0, stream>>>(bufH, as3, ad3, als, ald);
    agg32<<<(N_NODES * 32) / 256, 256, 0, stream>>>(bufH, als, ald, rowptr, srclist, b3, bufF);
    pool32<<<64, 256, 0, stream>>>(bufF, (float*)d_out);
}

// Round 2
// 840.741 us; speedup vs baseline: 1.1777x; 1.1777x over previous
//
#include <hip/hip_runtime.h>

// GAT (3-layer) on MI355X.
// R1: unroll aggregation edge-loops x4 (4 independent gather chains in flight)
// to fix the latency-bound inner loop (R0: VALUBusy 51%, hbm 34%, VGPR=12).

constexpr int N_NODES = 100000;
constexpr int E_IN    = 1600000;
constexpr int E_TOT   = E_IN + N_NODES;   // + self loops
constexpr float NEG   = 0.2f;

// ---------------- CSR build ----------------

__global__ void count_deg(const int* __restrict__ ei, int* __restrict__ deg) {
    int e = blockIdx.x * 256 + threadIdx.x;
    if (e >= E_TOT) return;
    int d = (e < E_IN) ? ei[E_IN + e] : (e - E_IN);
    atomicAdd(&deg[d], 1);
}

__global__ void scan_partial(const int* __restrict__ deg, int* __restrict__ bsum) {
    __shared__ int lds[256];
    int i = blockIdx.x * 256 + threadIdx.x;
    int v = (i < N_NODES) ? deg[i] : 0;
    lds[threadIdx.x] = v;
    __syncthreads();
    for (int s = 128; s > 0; s >>= 1) {
        if (threadIdx.x < s) lds[threadIdx.x] += lds[threadIdx.x + s];
        __syncthreads();
    }
    if (threadIdx.x == 0) bsum[blockIdx.x] = lds[0];
}

__global__ void scan_bsums(const int* __restrict__ bsum, int* __restrict__ bofs,
                           int* __restrict__ rowptr, int nb) {
    int lane = threadIdx.x;  // 64 threads
    int carry = 0;
    for (int base = 0; base < nb; base += 64) {
        int i = base + lane;
        int v = (i < nb) ? bsum[i] : 0;
        int x = v;
        #pragma unroll
        for (int d = 1; d < 64; d <<= 1) {
            int y = __shfl_up(x, d);
            if (lane >= d) x += y;
        }
        int excl = x - v + carry;
        if (i < nb) bofs[i] = excl;
        carry += __shfl(x, 63);
    }
    if (lane == 0) rowptr[N_NODES] = carry;  // == E_TOT
}

__global__ void scan_write(const int* __restrict__ deg, const int* __restrict__ bofs,
                           int* __restrict__ rowptr, int* __restrict__ cursor) {
    __shared__ int a[256], b[256];
    int t = threadIdx.x;
    int i = blockIdx.x * 256 + t;
    int v = (i < N_NODES) ? deg[i] : 0;
    a[t] = v;
    __syncthreads();
    int* src = a; int* dst = b;
    for (int d = 1; d < 256; d <<= 1) {
        dst[t] = src[t] + ((t >= d) ? src[t - d] : 0);
        __syncthreads();
        int* tmp = src; src = dst; dst = tmp;
    }
    int excl = src[t] - v + bofs[blockIdx.x];
    if (i < N_NODES) { rowptr[i] = excl; cursor[i] = excl; }
}

__global__ void fill_csr(const int* __restrict__ ei, int* __restrict__ cursor,
                         int* __restrict__ srclist) {
    int e = blockIdx.x * 256 + threadIdx.x;
    if (e >= E_TOT) return;
    int s, d;
    if (e < E_IN) { s = ei[e]; d = ei[E_IN + e]; }
    else          { s = e - E_IN; d = s; }
    int pos = atomicAdd(&cursor[d], 1);
    srclist[pos] = s;
}

// ---------------- GEMM: Y[N,COUT] = X[N,128] @ W[128,COUT] ----------------

template<int COUT>
__global__ __launch_bounds__(256) void gemm_k(const float* __restrict__ X,
                                              const float* __restrict__ Wg,
                                              float* __restrict__ Y) {
    constexpr int CG  = COUT / 4;
    constexpr int RG  = 256 / CG;
    constexpr int RPT = (COUT == 128) ? 4 : 2;
    constexpr int RB  = RG * RPT;
    constexpr int KCH = (COUT == 128) ? 64 : 128;
    constexpr int XSTR = 132;

    __shared__ float Wl[KCH * COUT];
    __shared__ float Xl[RB * XSTR];

    int t = threadIdx.x;
    int rbase = blockIdx.x * RB;

    for (int i = t; i < RB * 32; i += 256) {
        int r = i >> 5, c4 = i & 31;
        int gr = rbase + r; if (gr >= N_NODES) gr = N_NODES - 1;
        *(float4*)&Xl[r * XSTR + c4 * 4] = *(const float4*)&X[gr * 128 + c4 * 4];
    }

    int cg = t % CG, rg = t / CG;
    int c0 = cg * 4, r0 = rg * RPT;
    float4 acc[RPT];
    #pragma unroll
    for (int i = 0; i < RPT; i++) acc[i] = make_float4(0.f, 0.f, 0.f, 0.f);

    for (int ph = 0; ph < 128 / KCH; ++ph) {
        __syncthreads();
        for (int i = t * 4; i < KCH * COUT; i += 1024)
            *(float4*)&Wl[i] = *(const float4*)&Wg[ph * KCH * COUT + i];
        __syncthreads();
        for (int k4 = 0; k4 < KCH / 4; ++k4) {
            int kb = ph * KCH + k4 * 4;
            float4 wv[4], xv[RPT];
            #pragma unroll
            for (int kk = 0; kk < 4; kk++) wv[kk] = *(float4*)&Wl[(k4 * 4 + kk) * COUT + c0];
            #pragma unroll
            for (int i = 0; i < RPT; i++) xv[i] = *(float4*)&Xl[(r0 + i) * XSTR + kb];
            #pragma unroll
            for (int i = 0; i < RPT; i++) {
                const float* xs = (const float*)&xv[i];
                #pragma unroll
                for (int kk = 0; kk < 4; kk++) {
                    acc[i].x += xs[kk] * wv[kk].x;
                    acc[i].y += xs[kk] * wv[kk].y;
                    acc[i].z += xs[kk] * wv[kk].z;
                    acc[i].w += xs[kk] * wv[kk].w;
                }
            }
        }
    }
    #pragma unroll
    for (int i = 0; i < RPT; i++) {
        int gr = rbase + r0 + i;
        if (gr < N_NODES) *(float4*)&Y[gr * COUT + c0] = acc[i];
    }
}

// ---------------- per-node logit parts ----------------

template<int H, int HID>
__global__ void logits_k(const float* __restrict__ Hb, const float* __restrict__ a_src,
                         const float* __restrict__ a_dst,
                         float* __restrict__ als, float* __restrict__ ald) {
    int id = blockIdx.x * 256 + threadIdx.x;
    if (id >= N_NODES * H) return;
    int n = id / H, h = id % H;
    const float* row = &Hb[(n * H + h) * HID];
    float s = 0.f, dd = 0.f;
    #pragma unroll
    for (int j = 0; j < HID; j += 4) {
        float4 hv = *(const float4*)&row[j];
        float4 as = *(const float4*)&a_src[h * HID + j];
        float4 av = *(const float4*)&a_dst[h * HID + j];
        s  += hv.x * as.x + hv.y * as.y + hv.z * as.z + hv.w * as.w;
        dd += hv.x * av.x + hv.y * av.y + hv.z * av.z + hv.w * av.w;
    }
    als[id] = s; ald[id] = dd;
}

// ---------------- aggregation, one wave per node, x4 unrolled ----------------

__global__ __launch_bounds__(256) void agg128(const float* __restrict__ Hb,
        const float* __restrict__ als, const float* __restrict__ ald,
        const int* __restrict__ rowptr, const int* __restrict__ srclist,
        const float* __restrict__ bias, float* __restrict__ out) {
    int wave = (blockIdx.x * 256 + threadIdx.x) >> 6;
    int lane = threadIdx.x & 63;
    if (wave >= N_NODES) return;
    int d = wave;
    int c1 = lane, c2 = lane + 64;
    int h1 = lane >> 4, h2 = h1 + 4;
    float ad1 = ald[d * 8 + h1], ad2 = ald[d * 8 + h2];
    float acc1 = 0.f, acc2 = 0.f, den1 = 0.f, den2 = 0.f;
    int beg = rowptr[d], end = rowptr[d + 1];
    int j = beg;
    for (; j + 4 <= end; j += 4) {
        int s0 = srclist[j+0], s1 = srclist[j+1], s2 = srclist[j+2], s3 = srclist[j+3];
        const float* r0 = Hb + (size_t)s0 * 128;
        const float* r1 = Hb + (size_t)s1 * 128;
        const float* r2 = Hb + (size_t)s2 * 128;
        const float* r3 = Hb + (size_t)s3 * 128;
        float f0a = r0[c1], f0b = r0[c2];
        float f1a = r1[c1], f1b = r1[c2];
        float f2a = r2[c1], f2b = r2[c2];
        float f3a = r3[c1], f3b = r3[c2];
        float x0a = als[s0*8+h1], x0b = als[s0*8+h2];
        float x1a = als[s1*8+h1], x1b = als[s1*8+h2];
        float x2a = als[s2*8+h1], x2b = als[s2*8+h2];
        float x3a = als[s3*8+h1], x3b = als[s3*8+h2];
        float l, w;
        l = x0a + ad1; l = fmaxf(l, NEG*l); w = __expf(l); den1 += w; acc1 = fmaf(w, f0a, acc1);
        l = x0b + ad2; l = fmaxf(l, NEG*l); w = __expf(l); den2 += w; acc2 = fmaf(w, f0b, acc2);
        l = x1a + ad1; l = fmaxf(l, NEG*l); w = __expf(l); den1 += w; acc1 = fmaf(w, f1a, acc1);
        l = x1b + ad2; l = fmaxf(l, NEG*l); w = __expf(l); den2 += w; acc2 = fmaf(w, f1b, acc2);
        l = x2a + ad1; l = fmaxf(l, NEG*l); w = __expf(l); den1 += w; acc1 = fmaf(w, f2a, acc1);
        l = x2b + ad2; l = fmaxf(l, NEG*l); w = __expf(l); den2 += w; acc2 = fmaf(w, f2b, acc2);
        l = x3a + ad1; l = fmaxf(l, NEG*l); w = __expf(l); den1 += w; acc1 = fmaf(w, f3a, acc1);
        l = x3b + ad2; l = fmaxf(l, NEG*l); w = __expf(l); den2 += w; acc2 = fmaf(w, f3b, acc2);
    }
    for (; j < end; ++j) {
        int s = srclist[j];
        float fa = Hb[(size_t)s * 128 + c1];
        float fb = Hb[(size_t)s * 128 + c2];
        float l1 = als[s*8+h1] + ad1; l1 = fmaxf(l1, NEG*l1);
        float l2 = als[s*8+h2] + ad2; l2 = fmaxf(l2, NEG*l2);
        float w1 = __expf(l1), w2 = __expf(l2);
        den1 += w1; acc1 = fmaf(w1, fa, acc1);
        den2 += w2; acc2 = fmaf(w2, fb, acc2);
    }
    float o1 = acc1 / den1 + bias[c1]; o1 = o1 > 0.f ? o1 : 0.f;
    float o2 = acc2 / den2 + bias[c2]; o2 = o2 > 0.f ? o2 : 0.f;
    out[d * 128 + c1] = o1;
    out[d * 128 + c2] = o2;
}

__global__ __launch_bounds__(256) void agg32(const float* __restrict__ Hb,
        const float* __restrict__ als, const float* __restrict__ ald,
        const int* __restrict__ rowptr, const int* __restrict__ srclist,
        const float* __restrict__ bias, float* __restrict__ out) {
    int wave = (blockIdx.x * 256 + threadIdx.x) >> 6;
    int lane = threadIdx.x & 63;
    int d = wave * 2 + (lane >> 5);
    int c = lane & 31;
    if (d >= N_NODES) return;
    float adv = ald[d];
    float acc = 0.f, den = 0.f;
    int beg = rowptr[d], end = rowptr[d + 1];
    int j = beg;
    for (; j + 4 <= end; j += 4) {
        int s0 = srclist[j+0], s1 = srclist[j+1], s2 = srclist[j+2], s3 = srclist[j+3];
        float f0 = Hb[(size_t)s0 * 32 + c];
        float f1 = Hb[(size_t)s1 * 32 + c];
        float f2 = Hb[(size_t)s2 * 32 + c];
        float f3 = Hb[(size_t)s3 * 32 + c];
        float x0 = als[s0], x1 = als[s1], x2 = als[s2], x3 = als[s3];
        float l, w;
        l = x0 + adv; l = fmaxf(l, NEG*l); w = __expf(l); den += w; acc = fmaf(w, f0, acc);
        l = x1 + adv; l = fmaxf(l, NEG*l); w = __expf(l); den += w; acc = fmaf(w, f1, acc);
        l = x2 + adv; l = fmaxf(l, NEG*l); w = __expf(l); den += w; acc = fmaf(w, f2, acc);
        l = x3 + adv; l = fmaxf(l, NEG*l); w = __expf(l); den += w; acc = fmaf(w, f3, acc);
    }
    for (; j < end; ++j) {
        int s = srclist[j];
        float f = Hb[(size_t)s * 32 + c];
        float l = als[s] + adv; l = fmaxf(l, NEG*l);
        float w = __expf(l);
        den += w; acc = fmaf(w, f, acc);
    }
    out[d * 32 + c] = acc / den + bias[c];
}

// ---------------- global mean pool ----------------
__global__ void pool32(const float* __restrict__ h3, float* __restrict__ outp) {
    __shared__ float lds[256];
    int t = threadIdx.x;
    int c = t & 31, g = t >> 5;
    float acc = 0.f;
    for (int n = blockIdx.x * 8 + g; n < N_NODES; n += gridDim.x * 8)
        acc += h3[n * 32 + c];
    lds[t] = acc;
    __syncthreads();
    if (g == 0) {
        float s = 0.f;
        for (int gg = 0; gg < 8; ++gg) s += lds[gg * 32 + c];
        atomicAdd(&outp[c], s * (1.0f / N_NODES));
    }
}

// ---------------- launch ----------------

extern "C" void kernel_launch(void* const* d_in, const int* in_sizes, int n_in,
                              void* d_out, int out_size, void* d_ws, size_t ws_size,
                              hipStream_t stream) {
    (void)in_sizes; (void)n_in; (void)out_size; (void)ws_size;
    const float* x   = (const float*)d_in[0];
    const int*   ei  = (const int*)d_in[1];
    const float* W1  = (const float*)d_in[2];
    const float* as1 = (const float*)d_in[3];
    const float* ad1 = (const float*)d_in[4];
    const float* b1  = (const float*)d_in[5];
    const float* W2  = (const float*)d_in[6];
    const float* as2 = (const float*)d_in[7];
    const float* ad2 = (const float*)d_in[8];
    const float* b2  = (const float*)d_in[9];
    const float* W3  = (const float*)d_in[10];
    const float* as3 = (const float*)d_in[11];
    const float* ad3 = (const float*)d_in[12];
    const float* b3  = (const float*)d_in[13];

    char* ws = (char*)d_ws;
    size_t off = 0;
    auto carve = [&](size_t bytes) { void* p = ws + off; off += (bytes + 255) & ~size_t(255); return p; };
    float* bufH    = (float*)carve(size_t(N_NODES) * 128 * 4);
    float* bufF    = (float*)carve(size_t(N_NODES) * 128 * 4);
    float* als     = (float*)carve(size_t(N_NODES) * 8 * 4);
    float* ald     = (float*)carve(size_t(N_NODES) * 8 * 4);
    int*   deg     = (int*)carve(size_t(N_NODES) * 4);
    int*   rowptr  = (int*)carve(size_t(N_NODES + 1) * 4);
    int*   cursor  = (int*)carve(size_t(N_NODES) * 4);
    int*   bsum    = (int*)carve(512 * 4);
    int*   bofs    = (int*)carve(512 * 4);
    int*   srclist = (int*)carve(size_t(E_TOT) * 4);

    const int SCAN_B = (N_NODES + 255) / 256;
    const int EDGE_B = (E_TOT + 255) / 256;

    hipMemsetAsync(deg, 0, size_t(N_NODES) * 4, stream);
    hipMemsetAsync(d_out, 0, 32 * 4, stream);

    count_deg  <<<EDGE_B, 256, 0, stream>>>(ei, deg);
    scan_partial<<<SCAN_B, 256, 0, stream>>>(deg, bsum);
    scan_bsums <<<1, 64, 0, stream>>>(bsum, bofs, rowptr, SCAN_B);
    scan_write <<<SCAN_B, 256, 0, stream>>>(deg, bofs, rowptr, cursor);
    fill_csr   <<<EDGE_B, 256, 0, stream>>>(ei, cursor, srclist);

    gemm_k<128><<<N_NODES / 32, 256, 0, stream>>>(x, W1, bufH);
    logits_k<8, 16><<<(N_NODES * 8 + 255) / 256, 256, 0, stream>>>(bufH, as1, ad1, als, ald);
    agg128<<<(N_NODES * 64) / 256, 256, 0, stream>>>(bufH, als, ald, rowptr, srclist, b1, bufF);

    gemm_k<128><<<N_NODES / 32, 256, 0, stream>>>(bufF, W2, bufH);
    logits_k<8, 16><<<(N_NODES * 8 + 255) / 256, 256, 0, stream>>>(bufH, as2, ad2, als, ald);
    agg128<<<(N_NODES * 64) / 256, 256, 0, stream>>>(bufH, als, ald, rowptr, srclist, b2, bufF);

    gemm_k<32><<<(N_NODES + 63) / 64, 256, 0, stream>>>(bufF, W3, bufH);
    logits_k<1, 32><<<(N_NODES + 255) / 256, 256, 0, stream>>>(bufH, as3, ad3, als, ald);
    agg32<<<(N_NODES * 32) / 256, 256, 0, stream>>>(bufH, als, ald, rowptr, srclist, b3, bufF);
    pool32<<<64, 256, 0, stream>>>(bufF, (float*)d_out);
}